// Round 9
// baseline (174.441 us; speedup 1.0000x reference)
//
#include <hip/hip_runtime.h>

typedef short  s8v   __attribute__((ext_vector_type(8)));
typedef float  f32x4 __attribute__((ext_vector_type(4)));

#define SEQ 2048
#define WID 768

__device__ __forceinline__ unsigned fbits(float f) {
    union { float f; unsigned u; } v; v.f = f; return v.u;
}
__device__ __forceinline__ float bitsf(unsigned u) {
    union { unsigned u; float f; } v; v.u = u; return v.f;
}
__device__ __forceinline__ unsigned short f2b(float f) {
    unsigned u = fbits(f);
    return (unsigned short)((u + 0x7FFFu + ((u >> 16) & 1u)) >> 16);   // RNE
}
__device__ __forceinline__ unsigned packRNE(float a, float b) {
    unsigned ta = fbits(a) + 0x7FFFu + ((fbits(a) >> 16) & 1u);
    unsigned tb = fbits(b) + 0x7FFFu + ((fbits(b) >> 16) & 1u);
    return __builtin_amdgcn_perm(tb, ta, 0x07060302u);
}
__device__ __forceinline__ unsigned packTRUNC(float a, float b) {
    return __builtin_amdgcn_perm(fbits(b), fbits(a), 0x07060302u);
}
__device__ __forceinline__ f32x4 zero4() { f32x4 z = {0.f, 0.f, 0.f, 0.f}; return z; }

// ---------------------------------------------------------------------------
// convert: blocks [0,512): mask -> PM (verbatim verified).  [512,584):
// W -> WF bf16 B-frag-tiled (verbatim verified R8 logic).
// ---------------------------------------------------------------------------
__global__ __launch_bounds__(256) void convert_kernel(
    const int* __restrict__ mask,
    const float* __restrict__ Wq, const float* __restrict__ Wk, const float* __restrict__ Wv,
    unsigned* __restrict__ PM, unsigned short* __restrict__ WF)
{
    const int tid = threadIdx.x;
    const int blk = blockIdx.x;
    if (blk < 512) {
        const int gid  = blk * 4 + (tid >> 6);
        const int lane = tid & 63, quad = lane >> 4, c = lane & 15;
        const int qb = gid >> 5, kb = gid & 31;
        unsigned w = 0;
        #pragma unroll
        for (int mt = 0; mt < 2; ++mt)
            #pragma unroll
            for (int i = 0; i < 4; ++i) {
                const int q = qb * 32 + mt * 16 + quad * 4 + i;
                const int4 mm = *(const int4*)&mask[(size_t)q * SEQ + kb * 64 + 4 * c];
                if (mm.x) w |= 1u << (mt * 16 + i * 4 + 0);
                if (mm.y) w |= 1u << (mt * 16 + i * 4 + 1);
                if (mm.z) w |= 1u << (mt * 16 + i * 4 + 2);
                if (mm.w) w |= 1u << (mt * 16 + i * 4 + 3);
            }
        PM[(size_t)gid * 64 + lane] = w;
    } else {
        const int s2 = (blk - 512) * 256 + tid;       // 0 .. 18431
        const int chunk = s2 >> 6, l = s2 & 63;
        const int ntg = chunk / 24, r = chunk - ntg * 24;
        const int kc = r >> 1, h = r & 1;
        const int mat = ntg >> 2;
        const int col = (ntg & 3) * 16 + (l & 15);
        const int k0 = kc * 64 + h * 32 + (l >> 4) * 8;
        const float* Wm = (mat == 0) ? Wq : (mat == 1) ? Wk : Wv;
        float p[8];
        #pragma unroll
        for (int j = 0; j < 8; ++j) p[j] = Wm[(size_t)(k0 + j) * 64 + col];
        uint4 w;
        w.x = packRNE(p[0], p[1]); w.y = packRNE(p[2], p[3]);
        w.z = packRNE(p[4], p[5]); w.w = packRNE(p[6], p[7]);
        *(uint4*)&WF[(size_t)s2 * 8] = w;
    }
}

// ---------------------------------------------------------------------------
// proj: barrier-free wave-autonomous bf16 GEMM.  1024 blocks x 256 thr
// (4 blocks/CU, 16 waves/CU).  Block = 16 rows x 192 cols; wave = 16 x 48
// (c0w = wv*48), FULL K fully unrolled (24 x BK=32).  A-frags gathered
// direct from fp32 x (lane c = row, quad = k-offset; 4 packRNE/iter);
// B-frags direct from L2-hot frag-tiled WF (1KB coalesced).  Zero barriers
// until the epilogue.  Epilogue: verified R7 frag-tiled QF/KF/VF writeback.
// ---------------------------------------------------------------------------
__global__ __launch_bounds__(256, 4) void qkv_proj_kernel(
    const float* __restrict__ x, const unsigned short* __restrict__ WF,
    const float* __restrict__ bq, const float* __restrict__ bk, const float* __restrict__ bv,
    unsigned short* __restrict__ QF, unsigned short* __restrict__ KF,
    unsigned short* __restrict__ VF)
{
    __shared__ unsigned short St[16][208];

    const int tid = threadIdx.x;
    const int wv = tid >> 6, lane = tid & 63, quad = lane >> 4, c = lane & 15;
    const int rowb = blockIdx.x * 16;
    const int c0w  = wv * 48;

    float bias[3];
    #pragma unroll
    for (int nt = 0; nt < 3; ++nt) {
        int col = c0w + nt * 16 + c;
        const float* B = (col < 64) ? bq : (col < 128) ? bk : bv;
        bias[nt] = B[col & 63];
    }

    const float* xrow = x + (size_t)(rowb + c) * WID + quad * 8;

    f32x4 acc[3];
    #pragma unroll
    for (int nt = 0; nt < 3; ++nt) acc[nt] = zero4();

    #pragma unroll
    for (int kc = 0; kc < 24; ++kc) {
        float4 f0 = *(const float4*)&xrow[kc * 32];
        float4 f1 = *(const float4*)&xrow[kc * 32 + 4];
        union { uint4 u; s8v v; } bf[3];
        #pragma unroll
        for (int nt = 0; nt < 3; ++nt) {
            const int ntg = wv * 3 + nt;
            bf[nt].u = *(const uint4*)&WF[(((size_t)ntg * 12 + (kc >> 1)) * 2 + (kc & 1)) * 512 + lane * 8];
        }
        union { uint4 u; s8v v; } af;
        af.u.x = packRNE(f0.x, f0.y);
        af.u.y = packRNE(f0.z, f0.w);
        af.u.z = packRNE(f1.x, f1.y);
        af.u.w = packRNE(f1.z, f1.w);
        #pragma unroll
        for (int nt = 0; nt < 3; ++nt)
            acc[nt] = __builtin_amdgcn_mfma_f32_16x16x32_bf16(af.v, bf[nt].v, acc[nt], 0, 0, 0);
    }

    // ---- epilogue: bias + stage 16x192 bf16 tile, one barrier, writeback
    #pragma unroll
    for (int nt = 0; nt < 3; ++nt)
        #pragma unroll
        for (int i = 0; i < 4; ++i)
            St[quad * 4 + i][c0w + nt * 16 + c] = f2b(acc[nt][i] + bias[nt]);
    __syncthreads();

    const int kb  = rowb >> 6;
    const int q0k = (rowb & 63) >> 2;    // KF c-offset
    const int ks0 = (rowb & 63) >> 5;    // VF ks half
    const int qd0 = (rowb & 31) >> 3;    // VF qd base (0 or 2)

    if (tid < 128) {   // QF
        const int ks = tid >> 6, l = tid & 63, qd = l >> 4, cc = l & 15;
        uint4 v = *(uint4*)&St[cc][ks * 32 + qd * 8];
        *(uint4*)&QF[(((size_t)(rowb >> 4)) * 2 + ks) * 512 + (size_t)l * 8] = v;
    } else {           // KF
        const int u = tid - 128;
        const int ks = u >> 6, nt = (u >> 4) & 3, qd = (u >> 2) & 3, cc = u & 3;
        uint4 v = *(uint4*)&St[4 * cc + nt][64 + ks * 32 + qd * 8];
        *(uint4*)&KF[(((size_t)kb * 8 + ks * 4 + nt) * 64 + qd * 16 + q0k + cc) * 8] = v;
    }
    if (tid < 128) {   // VF
        const int d = tid >> 1, jj = tid & 1, qd = qd0 + jj;
        const int nt = d >> 4, cc = d & 15;
        unsigned short p[8];
        #pragma unroll
        for (int s = 0; s < 8; ++s) p[s] = St[jj * 8 + s][128 + d];
        uint4 w;
        w.x = (unsigned)p[0] | ((unsigned)p[1] << 16);
        w.y = (unsigned)p[2] | ((unsigned)p[3] << 16);
        w.z = (unsigned)p[4] | ((unsigned)p[5] << 16);
        w.w = (unsigned)p[6] | ((unsigned)p[7] << 16);
        *(uint4*)&VF[(((size_t)kb * 8 + ks0 * 4 + nt) * 64 + qd * 16 + cc) * 8] = w;
    }
}

// ---------------------------------------------------------------------------
// attn: barrier-free flash attention, MFMA bf16, fixed-shift softmax
// (identical math to R8, verified).  256 thr = 4 waves = 4 key-slices of
// 512 keys; wave tile 16q.  Grid 1024 (bb = blk&7 XCD swizzle, 4 blocks/CU,
// 16 waves/CU).  K/V frags direct from L2-hot frag-tiled KF/VF (1KB
// coalesced loads).  ZERO barriers in the (fully unrolled) K-loop; Ps is
// wave-private LDS.  kf regs die before vf loads (no spills at 128 cap).
// One barrier before the 4-slice merge.
// ---------------------------------------------------------------------------
__global__ __launch_bounds__(256, 4) void attn_kernel(
    const unsigned short* __restrict__ QF, const unsigned short* __restrict__ KF,
    const unsigned short* __restrict__ VF, const unsigned* __restrict__ PM,
    float* __restrict__ out)
{
    __shared__ unsigned short Ps[4][16][72];
    __shared__ float Obuf[16][68];
    __shared__ float Lbuf[16];

    const int tid = threadIdx.x;
    const int wv = tid >> 6, lane = tid & 63, quad = lane >> 4, c = lane & 15;
    const int blk = blockIdx.x;
    const int bb = blk & 7, g = blk >> 3;      // batch, 16-q group [0,128)
    const int qb32 = g >> 1, mtq = g & 1;

    #pragma unroll
    for (int j = 0; j < 5; ++j) {
        int idx = tid + 256 * j;
        if (idx < 16 * 68) ((float*)Obuf)[idx] = 0.f;
    }
    if (tid < 16) Lbuf[tid] = 0.f;

    // Q frags (coalesced 1KB loads)
    s8v qf[2];
    {
        const size_t qgrp = (size_t)bb * 128 + g;
        #pragma unroll
        for (int ks = 0; ks < 2; ++ks)
            qf[ks] = *(const s8v*)&QF[(qgrp * 2 + ks) * 512 + (size_t)lane * 8];
    }

    f32x4 O[4];
    float lro[4];
    #pragma unroll
    for (int nt = 0; nt < 4; ++nt) O[nt] = zero4();
    #pragma unroll
    for (int i = 0; i < 4; ++i) lro[i] = 0.f;

    #pragma unroll
    for (int kt = 0; kt < 8; ++kt) {
        const int kb = wv * 8 + kt;                      // 64-key tile [0,32)
        const size_t kbg = (size_t)bb * 32 + kb;
        const unsigned pm = PM[(size_t)(qb32 * 32 + kb) * 64 + lane];
        const unsigned pmh = pm >> (mtq * 16);

        // ---- S = Q K^T (kf dies right after)
        f32x4 S[4];
        #pragma unroll
        for (int nt = 0; nt < 4; ++nt) S[nt] = zero4();
        {
            s8v kf[8];
            #pragma unroll
            for (int ch = 0; ch < 8; ++ch)
                kf[ch] = *(const s8v*)&KF[(kbg * 8 + ch) * 512 + (size_t)lane * 8];
            #pragma unroll
            for (int ks = 0; ks < 2; ++ks)
                #pragma unroll
                for (int nt = 0; nt < 4; ++nt)
                    S[nt] = __builtin_amdgcn_mfma_f32_16x16x32_bf16(qf[ks], kf[ks * 4 + nt], S[nt], 0, 0, 0);
        }

        // ---- V frags issued now; latency covered by softmax VALU
        s8v vf[8];
        #pragma unroll
        for (int ch = 0; ch < 8; ++ch)
            vf[ch] = *(const s8v*)&VF[(kbg * 8 + ch) * 512 + (size_t)lane * 8];

        // ---- fixed-shift softmax: p = 2^(s*0.125/ln2 - 15/ln2), masked -> 0
        #pragma unroll
        for (int i = 0; i < 4; ++i) {
            float p4[4];
            #pragma unroll
            for (int nt = 0; nt < 4; ++nt) {
                float e = exp2f(fmaf(S[nt][i], 0.18033688011112042f, -21.640425613334451f));
                p4[nt] = ((pmh >> (i * 4 + nt)) & 1u) ? e : 0.f;
            }
            unsigned u0 = packTRUNC(p4[0], p4[1]);
            unsigned u1 = packTRUNC(p4[2], p4[3]);
            lro[i] += bitsf(u0 << 16) + bitsf(u0 & 0xFFFF0000u)
                    + bitsf(u1 << 16) + bitsf(u1 & 0xFFFF0000u);
            *(uint2*)&Ps[wv][quad * 4 + i][4 * c] = make_uint2(u0, u1);
        }

        // ---- O += P V  (Ps wave-private: lgkm ordering, no barrier)
        #pragma unroll
        for (int ks = 0; ks < 2; ++ks) {
            s8v a = *(const s8v*)&Ps[wv][c][ks * 32 + quad * 8];
            #pragma unroll
            for (int nt = 0; nt < 4; ++nt)
                O[nt] = __builtin_amdgcn_mfma_f32_16x16x32_bf16(a, vf[ks * 4 + nt], O[nt], 0, 0, 0);
        }
    }

    // ---- merge 4 slices (one barrier orders zeroing before atomics)
    __syncthreads();
    #pragma unroll
    for (int i = 0; i < 4; ++i) {
        float l = lro[i];
        l += __shfl_xor(l, 1);
        l += __shfl_xor(l, 2);
        l += __shfl_xor(l, 4);
        l += __shfl_xor(l, 8);
        if (c == 0) atomicAdd(&Lbuf[quad * 4 + i], l);
        #pragma unroll
        for (int nt = 0; nt < 4; ++nt)
            atomicAdd(&Obuf[quad * 4 + i][nt * 16 + c], O[nt][i]);
    }
    __syncthreads();
    {
        const int r = tid >> 4, d4 = (tid & 15) * 4;
        const float invL = 1.0f / Lbuf[r];
        float4 v = *(float4*)&Obuf[r][d4];
        float4 o = make_float4(v.x * invL, v.y * invL, v.z * invL, v.w * invL);
        *(float4*)&out[((size_t)bb * SEQ + g * 16 + r) * 64 + d4] = o;
    }
}

extern "C" void kernel_launch(void* const* d_in, const int* in_sizes, int n_in,
                              void* d_out, int out_size, void* d_ws, size_t ws_size,
                              hipStream_t stream)
{
    const float* x    = (const float*)d_in[0];
    const float* Wq   = (const float*)d_in[1];
    const float* bq   = (const float*)d_in[2];
    const float* Wk   = (const float*)d_in[3];
    const float* bk   = (const float*)d_in[4];
    const float* Wv   = (const float*)d_in[5];
    const float* bv   = (const float*)d_in[6];
    const int*   mask = (const int*)d_in[7];
    float* out = (float*)d_out;

    // ws: QF/KF/VF 2MB each + WF 288KB + PM 512KB ≈ 6.8 MB
    unsigned short* QF = (unsigned short*)d_ws;
    unsigned short* KF = QF + (size_t)16384 * 64;
    unsigned short* VF = KF + (size_t)16384 * 64;
    unsigned short* WF = VF + (size_t)16384 * 64;
    unsigned*       PM = (unsigned*)(WF + (size_t)192 * WID);

    convert_kernel<<<584, 256, 0, stream>>>(mask, Wq, Wk, Wv, PM, WF);
    qkv_proj_kernel<<<1024, 256, 0, stream>>>(x, WF, bq, bk, bv, QF, KF, VF);
    attn_kernel<<<1024, 256, 0, stream>>>(QF, KF, VF, PM, out);
}